// Round 14
// baseline (203.931 us; speedup 1.0000x reference)
//
#include <hip/hip_runtime.h>
#include <hip/hip_bf16.h>

#define N_NODES 4096
#define DIM 256
#define NHEAD 4
#define NEDGE 131072
#define MWORDS 128           // 4096 bits / 32 per mask row
#define MAXDEG 192           // mean deg ~65 (Poisson); 192 is >15 sigma
#define GBK 64               // GEMM K-step
#define MASK_BLOCKS 528      // (NEDGE + N_NODES) / 256

typedef unsigned short ushort_t;
typedef __attribute__((ext_vector_type(8))) short short8;
typedef __attribute__((ext_vector_type(4))) float f32x4;

__device__ __forceinline__ ushort_t f2bf(float f) {
    unsigned u = __float_as_uint(f);
    unsigned r = u + 0x7FFFu + ((u >> 16) & 1u);   // round-to-nearest-even
    return (ushort_t)(r >> 16);
}
__device__ __forceinline__ float bf2f(ushort_t u) {
    return __uint_as_float((unsigned)u << 16);
}

// ---------------------------------------------------------------- fused mask build + converts
// blocks [0, 528): mask build (atomicOr into pre-zeroed bitmask)
// blocks [528, 2832): fp32->bf16 converts, segments:
//   x 1048576 | Wq 262144 | Wk 262144 | Wv 262144 | Wo 262144 | Wp 262144
__global__ __launch_bounds__(256) void init_kernel(
    const int* __restrict__ ei, unsigned* __restrict__ mask,
    const float* __restrict__ x,  const float* __restrict__ Wq,
    const float* __restrict__ Wk, const float* __restrict__ Wv,
    const float* __restrict__ Wo, const float* __restrict__ Wp,
    ushort_t* __restrict__ xb, ushort_t* __restrict__ wstack,
    ushort_t* __restrict__ wob, ushort_t* __restrict__ wpb) {
    const int bid = blockIdx.x;
    if (bid < MASK_BLOCKS) {
        const int t = bid * 256 + threadIdx.x;
        if (t < NEDGE) {
            const int r = ei[t] & (N_NODES - 1);
            const int c = ei[NEDGE + t] & (N_NODES - 1);
            atomicOr(&mask[r * MWORDS + (c >> 5)], 1u << (c & 31));
            atomicOr(&mask[c * MWORDS + (r >> 5)], 1u << (r & 31));
        } else if (t < NEDGE + N_NODES) {
            const int i = t - NEDGE;
            atomicOr(&mask[i * MWORDS + (i >> 5)], 1u << (i & 31));
        }
        return;
    }
    const int e = ((bid - MASK_BLOCKS) * 256 + threadIdx.x) << 2;
    const float* src; ushort_t* dst; int off;
    if (e < 1048576)      { src = x;  dst = xb;              off = e; }
    else if (e < 1310720) { src = Wq; dst = wstack;          off = e - 1048576; }
    else if (e < 1572864) { src = Wk; dst = wstack + 262144; off = e - 1310720; }
    else if (e < 1835008) { src = Wv; dst = wstack + 524288; off = e - 1572864; }
    else if (e < 2097152) { src = Wo; dst = wob;             off = e - 1835008; }
    else                  { src = Wp; dst = wpb;             off = e - 2097152; }
    const float4 v = *(const float4*)(src + off);
    ushort4 r;
    r.x = f2bf(v.x); r.y = f2bf(v.y); r.z = f2bf(v.z); r.w = f2bf(v.w);
    *(ushort4*)(dst + off) = r;
}

// ---------------------------------------------------------------- MFMA bf16 GEMM
// D[ch][node] = sum_k Wb[ch][k] * Xb[node][k]  (+bias[ch]); 128x128 tile, 4 waves.
// MODE 0: QKV -> qb bf16 [h][node][256] + kvh per-head records [h][node][k256|v256].
// MODE 1: headout -> concat bf16 [node][1024] (z = head).
template <int MODE>
__global__ __launch_bounds__(256) void mfma_gemm_kernel(
    const ushort_t* __restrict__ Wb, const ushort_t* __restrict__ Xb,
    const float* __restrict__ b0, const float* __restrict__ b1,
    const float* __restrict__ b2,
    ushort_t* __restrict__ qb, ushort_t* __restrict__ kvh,
    void* __restrict__ outp, int K) {
    __shared__ ushort_t Wt[128][GBK + 8];
    __shared__ ushort_t Xt[128][GBK + 8];
    const int tid = threadIdx.x;
    const int lane = tid & 63;
    const int wid = tid >> 6;
    const int wr = wid >> 1, wc = wid & 1;
    const int zoff = (MODE == 1) ? blockIdx.z : 0;
    const ushort_t* Wp_ = Wb + (size_t)zoff * (256 * 256);
    const ushort_t* Xp_ = Xb + (size_t)zoff * ((size_t)N_NODES * 256);
    const int chB = blockIdx.x * 128;
    const int ndB = blockIdx.y * 128;

    f32x4 acc[4][4] = {};

    for (int kt = 0; kt < K; kt += GBK) {
        short8 wreg[4], xreg[4];
#pragma unroll
        for (int i = 0; i < 4; ++i) {
            const int flat = tid + (i << 8);
            const int r = flat >> 3, s = flat & 7;
            wreg[i] = *(const short8*)(Wp_ + (size_t)(chB + r) * K + kt + (s << 3));
            xreg[i] = *(const short8*)(Xp_ + (size_t)(ndB + r) * K + kt + (s << 3));
        }
        __syncthreads();
#pragma unroll
        for (int i = 0; i < 4; ++i) {
            const int flat = tid + (i << 8);
            const int r = flat >> 3, s = flat & 7;
            *(short8*)&Wt[r][s << 3] = wreg[i];
            *(short8*)&Xt[r][s << 3] = xreg[i];
        }
        __syncthreads();
#pragma unroll
        for (int kk = 0; kk < 2; ++kk) {
            short8 af[4], bf[4];
            const int ko = (kk << 5) + ((lane >> 4) << 3);
#pragma unroll
            for (int m = 0; m < 4; ++m)
                af[m] = *(const short8*)&Wt[wr * 64 + m * 16 + (lane & 15)][ko];
#pragma unroll
            for (int n = 0; n < 4; ++n)
                bf[n] = *(const short8*)&Xt[wc * 64 + n * 16 + (lane & 15)][ko];
#pragma unroll
            for (int m = 0; m < 4; ++m)
#pragma unroll
                for (int n = 0; n < 4; ++n)
                    acc[m][n] = __builtin_amdgcn_mfma_f32_16x16x32_bf16(
                        af[m], bf[n], acc[m][n], 0, 0, 0);
        }
    }

    // ---- epilogue
    const int lhi = lane >> 4;       // 0..3
    const int llo = lane & 15;
    int op = 0, h = 0;
    if (MODE == 0) { op = chB >> 10; h = (chB >> 8) & 3; }
#pragma unroll
    for (int m = 0; m < 4; ++m) {
        const int ch = chB + wr * 64 + m * 16 + (lhi << 2);   // +j over 4 regs
        float4 bia;
        if (MODE == 0) {
            const float* bb = (op == 0 ? b0 : op == 1 ? b1 : b2) + (h << 8);
            bia = *(const float4*)&bb[ch & 255];
        } else {
            bia = *(const float4*)&b0[(zoff << 8) + ch];
        }
#pragma unroll
        for (int n = 0; n < 4; ++n) {
            const int node = ndB + wc * 64 + n * 16 + llo;
            const float v0 = acc[m][n][0] + bia.x;
            const float v1 = acc[m][n][1] + bia.y;
            const float v2 = acc[m][n][2] + bia.z;
            const float v3 = acc[m][n][3] + bia.w;
            ushort4 r;
            r.x = f2bf(v0); r.y = f2bf(v1); r.z = f2bf(v2); r.w = f2bf(v3);
            if (MODE == 1) {
                *(ushort4*)&((ushort_t*)outp)[(size_t)node * 1024 + (zoff << 8) + ch] = r;
            } else {
                const int c = ch & 255;
                if (op == 0)
                    *(ushort4*)&qb[(((size_t)h * N_NODES + node) << 8) + c] = r;
                else if (op == 1)
                    *(ushort4*)&kvh[(((size_t)h * N_NODES + node) << 9) + c] = r;
                else
                    *(ushort4*)&kvh[(((size_t)h * N_NODES + node) << 9) + 256 + c] = r;
            }
        }
    }
}

// ---------------------------------------------------------------- final proj + fused LayerNorm
// out[node][f] = LN( sum_k concat[node][k]*Wp[f][k] + bp[f] ) * gamma + beta
// Tile: ALL 256 f x 64 nodes per block (wave wid owns f quadrant wid*64..+63)
// -> block holds complete output rows; LN via cross-wave LDS partial sums.
__global__ __launch_bounds__(256) void final_ln_kernel(
    const ushort_t* __restrict__ Wb,      // wpb [256][1024]
    const ushort_t* __restrict__ Xb,      // concatb [4096][1024]
    const float* __restrict__ bp,
    const float* __restrict__ gamma, const float* __restrict__ beta,
    float* __restrict__ out) {
    __shared__ ushort_t Wt[256][GBK + 8];
    __shared__ ushort_t Xt[64][GBK + 8];
    __shared__ float redS[4][64];
    __shared__ float redQ[4][64];
    const int tid = threadIdx.x;
    const int lane = tid & 63;
    const int wid = tid >> 6;
    const int ndB = blockIdx.x * 64;

    f32x4 acc[4][4] = {};

    for (int kt = 0; kt < 1024; kt += GBK) {
        short8 wreg[8], xreg[2];
#pragma unroll
        for (int i = 0; i < 8; ++i) {
            const int flat = tid + (i << 8);
            const int r = flat >> 3, s = flat & 7;
            wreg[i] = *(const short8*)(Wb + (size_t)r * 1024 + kt + (s << 3));
        }
#pragma unroll
        for (int i = 0; i < 2; ++i) {
            const int flat = tid + (i << 8);
            const int r = flat >> 3, s = flat & 7;
            xreg[i] = *(const short8*)(Xb + (size_t)(ndB + r) * 1024 + kt + (s << 3));
        }
        __syncthreads();
#pragma unroll
        for (int i = 0; i < 8; ++i) {
            const int flat = tid + (i << 8);
            const int r = flat >> 3, s = flat & 7;
            *(short8*)&Wt[r][s << 3] = wreg[i];
        }
#pragma unroll
        for (int i = 0; i < 2; ++i) {
            const int flat = tid + (i << 8);
            const int r = flat >> 3, s = flat & 7;
            *(short8*)&Xt[r][s << 3] = xreg[i];
        }
        __syncthreads();
#pragma unroll
        for (int kk = 0; kk < 2; ++kk) {
            short8 af[4], bf[4];
            const int ko = (kk << 5) + ((lane >> 4) << 3);
#pragma unroll
            for (int m = 0; m < 4; ++m)
                af[m] = *(const short8*)&Wt[wid * 64 + m * 16 + (lane & 15)][ko];
#pragma unroll
            for (int n = 0; n < 4; ++n)
                bf[n] = *(const short8*)&Xt[n * 16 + (lane & 15)][ko];
#pragma unroll
            for (int m = 0; m < 4; ++m)
#pragma unroll
                for (int n = 0; n < 4; ++n)
                    acc[m][n] = __builtin_amdgcn_mfma_f32_16x16x32_bf16(
                        af[m], bf[n], acc[m][n], 0, 0, 0);
        }
    }

    const int lhi = lane >> 4;
    const int llo = lane & 15;
    // bias add + per-node partial sums (this thread: 16 f-values per node, 4 nodes)
    float vout[4][4][4];
    float psum[4] = {0.f, 0.f, 0.f, 0.f};
    float psq[4]  = {0.f, 0.f, 0.f, 0.f};
#pragma unroll
    for (int m = 0; m < 4; ++m) {
        const int f0 = wid * 64 + m * 16 + (lhi << 2);
        const float4 bia = *(const float4*)&bp[f0];
#pragma unroll
        for (int n = 0; n < 4; ++n) {
            const float v0 = acc[m][n][0] + bia.x;
            const float v1 = acc[m][n][1] + bia.y;
            const float v2 = acc[m][n][2] + bia.z;
            const float v3 = acc[m][n][3] + bia.w;
            vout[m][n][0] = v0; vout[m][n][1] = v1;
            vout[m][n][2] = v2; vout[m][n][3] = v3;
            psum[n] += v0 + v1 + v2 + v3;
            psq[n]  += v0 * v0 + v1 * v1 + v2 * v2 + v3 * v3;
        }
    }
    // reduce across lhi (lanes llo, llo+16, llo+32, llo+48 share the node)
#pragma unroll
    for (int n = 0; n < 4; ++n) {
        psum[n] += __shfl_xor(psum[n], 16);
        psum[n] += __shfl_xor(psum[n], 32);
        psq[n]  += __shfl_xor(psq[n], 16);
        psq[n]  += __shfl_xor(psq[n], 32);
    }
    if (lhi == 0) {
#pragma unroll
        for (int n = 0; n < 4; ++n) {
            redS[wid][n * 16 + llo] = psum[n];
            redQ[wid][n * 16 + llo] = psq[n];
        }
    }
    __syncthreads();
    float mean[4], inv[4];
#pragma unroll
    for (int n = 0; n < 4; ++n) {
        const int nd = n * 16 + llo;
        const float S = redS[0][nd] + redS[1][nd] + redS[2][nd] + redS[3][nd];
        const float Q = redQ[0][nd] + redQ[1][nd] + redQ[2][nd] + redQ[3][nd];
        const float mu = S * (1.0f / DIM);
        const float var = Q * (1.0f / DIM) - mu * mu;
        mean[n] = mu;
        inv[n] = 1.0f / sqrtf(var + 1e-5f);
    }
#pragma unroll
    for (int m = 0; m < 4; ++m) {
        const int f0 = wid * 64 + m * 16 + (lhi << 2);
        const float4 gv = *(const float4*)&gamma[f0];
        const float4 bv = *(const float4*)&beta[f0];
#pragma unroll
        for (int n = 0; n < 4; ++n) {
            const int node = ndB + n * 16 + llo;
            float4 r;
            r.x = (vout[m][n][0] - mean[n]) * inv[n] * gv.x + bv.x;
            r.y = (vout[m][n][1] - mean[n]) * inv[n] * gv.y + bv.y;
            r.z = (vout[m][n][2] - mean[n]) * inv[n] * gv.z + bv.z;
            r.w = (vout[m][n][3] - mean[n]) * inv[n] * gv.w + bv.w;
            *(float4*)&out[(size_t)node * DIM + f0] = r;
        }
    }
}

// ---------------------------------------------------------------- sparse attention
// XCD-pinned per-head partition (proven: FETCH 364->37MB); atomic-free popcount+
// prefix-scan decode (proven: conflicts 901K->19K); 4-neighbor subgroup gather
// (proven: 110->62us). Unchanged from round 13.
__global__ __launch_bounds__(256) void attn_sparse_kernel(const unsigned* __restrict__ mask,
                                                          const ushort_t* __restrict__ qb,
                                                          const ushort_t* __restrict__ kvh,
                                                          ushort_t* __restrict__ ob) {
    __shared__ int nbr[4][MAXDEG];
    const int tid = threadIdx.x;
    const int w = tid >> 6;
    const int lane = tid & 63;
    const int xcd = blockIdx.x & 7;
    const int h = xcd >> 1;
    const int node = ((xcd & 1) << 11) + ((blockIdx.x >> 3) << 2) + w;

    const unsigned m0 = mask[node * MWORDS + lane];
    const unsigned m1 = mask[node * MWORDS + 64 + lane];
    const int c = __popc(m0) + __popc(m1);
    int s = c;
#pragma unroll
    for (int d = 1; d < 64; d <<= 1) {
        const int t = __shfl_up(s, d);
        if (lane >= d) s += t;
    }
    const int deg0 = __shfl(s, 63);
    const int deg = deg0 < MAXDEG ? deg0 : MAXDEG;
    int pos = s - c;
    unsigned mm = m0;
    int bj = lane << 5;
    while (mm) {
        const int b = __ffs(mm) - 1; mm &= mm - 1;
        if (pos < MAXDEG) nbr[w][pos] = bj + b;
        ++pos;
    }
    mm = m1; bj = (lane + 64) << 5;
    while (mm) {
        const int b = __ffs(mm) - 1; mm &= mm - 1;
        if (pos < MAXDEG) nbr[w][pos] = bj + b;
        ++pos;
    }
    __syncthreads();

    const int sub = lane >> 4;
    const int sl = lane & 15;

    const ushort_t* qp = qb + (((size_t)h * N_NODES + node) << 8) + (sl << 4);
    const short8 q0 = *(const short8*)qp;
    const short8 q1 = *(const short8*)(qp + 8);
    float qf[16];
#pragma unroll
    for (int i = 0; i < 8; ++i) {
        qf[i] = bf2f((ushort_t)q0[i]);
        qf[8 + i] = bf2f((ushort_t)q1[i]);
    }
    float oa[16];
#pragma unroll
    for (int i = 0; i < 16; ++i) oa[i] = 0.f;
    float denom = 0.f;

    const ushort_t* kbase = kvh + (((size_t)h * N_NODES) << 9) + (sl << 4);
    const float SC = 0.0625f * 1.44269504f;   // 1/sqrt(256) * log2(e)

    for (int n0 = 0; n0 < deg; n0 += 4) {
        const int idx = n0 + sub;
        const bool valid = idx < deg;
        const int j = nbr[w][valid ? idx : 0];
        const ushort_t* kp = kbase + ((size_t)j << 9);
        const short8 k0 = *(const short8*)kp;
        const short8 k1 = *(const short8*)(kp + 8);
        const short8 v0 = *(const short8*)(kp + 256);
        const short8 v1 = *(const short8*)(kp + 264);
        float p = 0.f;
#pragma unroll
        for (int i = 0; i < 8; ++i)
            p += qf[i] * bf2f((ushort_t)k0[i]) + qf[8 + i] * bf2f((ushort_t)k1[i]);
        p += __shfl_xor(p, 1);
        p += __shfl_xor(p, 2);
        p += __shfl_xor(p, 4);
        p += __shfl_xor(p, 8);
        const float wt = valid ? __builtin_amdgcn_exp2f(p * SC) : 0.f;
        denom += wt;
#pragma unroll
        for (int i = 0; i < 8; ++i) {
            oa[i] += wt * bf2f((ushort_t)v0[i]);
            oa[8 + i] += wt * bf2f((ushort_t)v1[i]);
        }
    }
    denom += __shfl_xor(denom, 16);
    denom += __shfl_xor(denom, 32);
#pragma unroll
    for (int i = 0; i < 16; ++i) {
        oa[i] += __shfl_xor(oa[i], 16);
        oa[i] += __shfl_xor(oa[i], 32);
    }
    if (sub == 0) {
        const float inv = 1.0f / denom;
        short8 r0, r1;
#pragma unroll
        for (int i = 0; i < 8; ++i) {
            r0[i] = (short)f2bf(oa[i] * inv);
            r1[i] = (short)f2bf(oa[8 + i] * inv);
        }
        ushort_t* op_ = ob + (((size_t)h * N_NODES + node) << 8) + (sl << 4);
        *(short8*)op_ = r0;
        *(short8*)(op_ + 8) = r1;
    }
}

// ---------------------------------------------------------------- launcher
extern "C" void kernel_launch(void* const* d_in, const int* in_sizes, int n_in,
                              void* d_out, int out_size, void* d_ws, size_t ws_size,
                              hipStream_t stream) {
    const float* x     = (const float*)d_in[0];
    const int*   ei    = (const int*)d_in[1];
    const float* Wq    = (const float*)d_in[2];
    const float* bq    = (const float*)d_in[3];
    const float* Wk    = (const float*)d_in[4];
    const float* bk    = (const float*)d_in[5];
    const float* Wv    = (const float*)d_in[6];
    const float* bv    = (const float*)d_in[7];
    const float* Wo    = (const float*)d_in[8];
    const float* bo    = (const float*)d_in[9];
    const float* Wp    = (const float*)d_in[10];
    const float* bp    = (const float*)d_in[11];
    const float* gamma = (const float*)d_in[12];
    const float* beta  = (const float*)d_in[13];
    float* outf = (float*)d_out;

    char* ws = (char*)d_ws;
    unsigned* mask    = (unsigned*)(ws);                          // 2 MB
    ushort_t* xb      = (ushort_t*)(ws + (size_t)( 2 << 20));     // 2 MB  bf16 [4096][256]
    ushort_t* qb      = (ushort_t*)(ws + (size_t)( 4 << 20));     // 8 MB  bf16 [h][n][256]
    ushort_t* kvh     = (ushort_t*)(ws + (size_t)(12 << 20));     // 16 MB bf16 [h][n][512]
    ushort_t* ob      = (ushort_t*)(ws + (size_t)(28 << 20));     // 8 MB  bf16 [h][n][256]
    ushort_t* concatb = (ushort_t*)(ws + (size_t)(36 << 20));     // 8 MB  bf16 [n][1024]
    ushort_t* wstack  = (ushort_t*)(ws + (size_t)(48 << 20));     // 1.5 MB bf16 [3072][256]
    ushort_t* wob     = (ushort_t*)(ws + (size_t)(50 << 20));     // 0.5 MB bf16 [1024][256]
    ushort_t* wpb     = (ushort_t*)(ws + (size_t)(51 << 20));     // 0.5 MB bf16 [256][1024]

    hipMemsetAsync(mask, 0, N_NODES * MWORDS * sizeof(unsigned), stream);

    init_kernel<<<MASK_BLOCKS + 2304, 256, 0, stream>>>(
        ei, mask, x, Wq, Wk, Wv, Wo, Wp, xb, wstack, wob, wpb);

    // QKV: R=3072 channels x M=4096 nodes, K=256
    mfma_gemm_kernel<0><<<dim3(24, 32), 256, 0, stream>>>(
        wstack, xb, bq, bk, bv, qb, kvh, nullptr, 256);

    attn_sparse_kernel<<<N_NODES, 256, 0, stream>>>(mask, qb, kvh, ob);

    // headout per head: R=256, M=4096, K=256 -> concat bf16
    mfma_gemm_kernel<1><<<dim3(2, 32, NHEAD), 256, 0, stream>>>(
        wob, ob, bo, nullptr, nullptr, nullptr, nullptr, concatb, 256);

    // final projection + fused LayerNorm: 64 blocks of 256f x 64 nodes
    final_ln_kernel<<<64, 256, 0, stream>>>(wpb, concatb, bp, gamma, beta, outf);
}